// Round 12
// baseline (70.918 us; speedup 1.0000x reference)
//
#include <hip/hip_runtime.h>

typedef float    f32x4  __attribute__((ext_vector_type(4)));
typedef short    s16x8  __attribute__((ext_vector_type(8)));
typedef unsigned uivec2 __attribute__((ext_vector_type(2)));
typedef unsigned uivec4 __attribute__((ext_vector_type(4)));

#define Tt 512
#define Ll 128
#define CH 32
#define CL 16
#define NR 31
#define NRECB 248        // recursion blocks (4 independent waves each = 992 runs)
#define NSCORE 256

// workspace float offsets (same as round 11, ~8.2 MB)
#define WS_PT 0
#define WS_TR 256
#define WS_KR 512
#define WS_KB (512 + 256*NR)
#define WS_RV (512 + 2*256*NR)
#define WS_BV (WS_RV + 256*NR*128)

__device__ __forceinline__ ushort bf16rn(float f) {   // RNE f32->bf16 (positive)
  unsigned u = __float_as_uint(f);
  u += 0x7FFFu + ((u >> 16) & 1u);
  return (ushort)(u >> 16);
}
__device__ __forceinline__ unsigned cvtpk(float a, float b) {
  unsigned d;
  asm("v_cvt_pk_bf16_f32 %0, %1, %2" : "=v"(d) : "v"(a), "v"(b));
  return d;
}
__device__ __forceinline__ float4 expf4(float4 v) {
  float4 r; r.x = __expf(v.x); r.y = __expf(v.y); r.z = __expf(v.z); r.w = __expf(v.w);
  return r;
}
__device__ __forceinline__ float4 mul4(float4 v, float s) {
  v.x *= s; v.y *= s; v.z *= s; v.w *= s; return v;
}

// One kernel, two roles by blockIdx parity (interleaved so score streaming
// overlaps recursion on every CU).
//  - score blocks: stream y_pred.y_true dot + one-hot labels -> trans gather.
//  - recursion blocks: 4 INDEPENDENT waves, each a full 16-batch chunk run:
//    per step U(16x128)@E(128x128) = 32 MFMAs in ONE wave. E in 128 VGPRs.
//    U round-trips a wave-PRIVATE LDS buffer: D-side 8x ds_write_b64 into
//    j-major [j][m] bf16, A-side 8x ds_read_b64_tr_b16 (HW transpose).
//    k-slot map j = 32kt+16(e>>2)+4q+(e&3) used for BOTH A and B (cancels).
//    Emission scaling on the A-read side (coalesced float4, 2-slot lookahead);
//    wave-uniform pivot renorm (readfirstlane) at k=9,15. ZERO barriers.
__global__ __attribute__((amdgpu_flat_work_group_size(256, 256),
                          amdgpu_waves_per_eu(1)))
void crf_main(const float* __restrict__ yt_g, const float* __restrict__ yp_g,
              const float* __restrict__ tr_g, float* __restrict__ wsf)
{
  __shared__ __align__(16) char smem[32768];
  const int tid = threadIdx.x, wv = tid >> 6, l = tid & 63;
  const int bid = blockIdx.x;

  bool isrec; int sidx = 0, ridx = 0;
  if (bid < 2 * NRECB) { isrec = (bid & 1); sidx = ridx = bid >> 1; }
  else { isrec = false; sidx = NRECB + (bid - 2 * NRECB); }

  if (!isrec) {
    // ================= score block =================
    int*   lab_s = (int*)smem;
    float* redp  = (float*)(smem + 2048);
    float* redt  = (float*)(smem + 2080);
    const int b = sidx;
    const float4* yp4 = (const float4*)(yp_g + (size_t)b * Tt * Ll);
    const float4* yt4 = (const float4*)(yt_g + (size_t)b * Tt * Ll);
    float pt = 0.f;
    #pragma unroll 4
    for (int i = 0; i < 64; ++i) {
      int f = tid + i * 256;
      float4 a = yp4[f], y = yt4[f];
      pt += a.x * y.x + a.y * y.y + a.z * y.z + a.w * y.w;
      int t = f >> 5, jb = (f & 31) << 2;
      if (y.x > .5f) lab_s[t] = jb;
      if (y.y > .5f) lab_s[t] = jb + 1;
      if (y.z > .5f) lab_s[t] = jb + 2;
      if (y.w > .5f) lab_s[t] = jb + 3;
    }
    __syncthreads();
    float trl = 0.f;
    for (int t0 = tid; t0 < Tt - 1; t0 += 256)
      trl += tr_g[lab_s[t0] * Ll + lab_s[t0 + 1]];
    #pragma unroll
    for (int o = 32; o; o >>= 1) { pt += __shfl_xor(pt, o); trl += __shfl_xor(trl, o); }
    if (l == 0) { redp[wv] = pt; redt[wv] = trl; }
    __syncthreads();
    if (tid == 0) {
      wsf[WS_PT + b] = redp[0] + redp[1] + redp[2] + redp[3];
      wsf[WS_TR + b] = redt[0] + redt[1] + redt[2] + redt[3];
    }
    return;
  }

  // ================= recursion wave =================
  const int task = ridx * 4 + wv;         // 0..991
  const bool FWD = task < 496;
  int g, c;
  if (FWD) { g = task / 31; c = task % 31; }
  else     { int t2 = task - 496; g = t2 / 31; c = t2 % 31 + 1; }
  const int b0  = g * 16;
  const int l15 = l & 15, q = l >> 4;
  const int t_hi = (c == CH - 1) ? (Tt - 1) : (c * CL + CL);
  const int t_lo = c * CL + 1;
  const int n    = FWD ? CL : (t_hi - t_lo + 1);   // 16, or 15 for bwd c=31

  // ---- E fragments in registers: Bf[tl][kt] slot e holds
  //      exp(trans) at (j_in = 32kt+16(e>>2)+4q+(e&3), j_out = l15+16tl) ----
  s16x8 Bf[8][4];
  if (FWD) {
    #pragma unroll
    for (int kt = 0; kt < 4; ++kt)
      #pragma unroll
      for (int e = 0; e < 8; ++e) {
        const int jin = 32 * kt + 16 * (e >> 2) + 4 * q + (e & 3);
        const float* rp_ = tr_g + jin * Ll + l15;
        #pragma unroll
        for (int tl = 0; tl < 8; ++tl)
          Bf[tl][kt][e] = (short)bf16rn(__expf(rp_[16 * tl]));
      }
  } else {
    #pragma unroll
    for (int tl = 0; tl < 8; ++tl) {
      const float* rp_ = tr_g + (l15 + 16 * tl) * Ll + 4 * q;
      #pragma unroll
      for (int kt = 0; kt < 4; ++kt)
        #pragma unroll
        for (int r = 0; r < 2; ++r) {
          float4 tv = *(const float4*)(rp_ + 32 * kt + 16 * r);
          Bf[tl][kt][4 * r + 0] = (short)bf16rn(__expf(tv.x));
          Bf[tl][kt][4 * r + 1] = (short)bf16rn(__expf(tv.y));
          Bf[tl][kt][4 * r + 2] = (short)bf16rn(__expf(tv.z));
          Bf[tl][kt][4 * r + 3] = (short)bf16rn(__expf(tv.w));
        }
    }
  }

  const unsigned sbase = (unsigned)(size_t)(&smem[0]);
  const unsigned wvoff = (unsigned)(wv * 8192);
  const unsigned lane8 = (unsigned)(l * 8);
  const int wroff = wv * 8192 + l15 * 32 + q * 8;
  const float* emb = yp_g + (size_t)(b0 + l15) * (Tt * Ll) + 4 * q;
  float Kacc = 0.f;

#define LOADSLOT(S, TAU)                                                      \
  { const float* ep_ = emb + (size_t)(TAU) * Ll;                              \
    S##0 = *(const float4*)(ep_ + 0);   S##1 = *(const float4*)(ep_ + 16);    \
    S##2 = *(const float4*)(ep_ + 32);  S##3 = *(const float4*)(ep_ + 48);    \
    S##4 = *(const float4*)(ep_ + 64);  S##5 = *(const float4*)(ep_ + 80);    \
    S##6 = *(const float4*)(ep_ + 96);  S##7 = *(const float4*)(ep_ + 112); }

#define TRREAD8(RBUF, T0,T1,T2,T3,T4,T5,T6,T7)                                \
  { unsigned ra_ = sbase + wvoff + (unsigned)((RBUF) * 4096) + lane8;         \
    asm volatile(                                                             \
      "ds_read_b64_tr_b16 %0, %8 offset:0\n\t"                                \
      "ds_read_b64_tr_b16 %1, %8 offset:512\n\t"                              \
      "ds_read_b64_tr_b16 %2, %8 offset:1024\n\t"                             \
      "ds_read_b64_tr_b16 %3, %8 offset:1536\n\t"                             \
      "ds_read_b64_tr_b16 %4, %8 offset:2048\n\t"                             \
      "ds_read_b64_tr_b16 %5, %8 offset:2560\n\t"                             \
      "ds_read_b64_tr_b16 %6, %8 offset:3072\n\t"                             \
      "ds_read_b64_tr_b16 %7, %8 offset:3584\n\t"                             \
      "s_waitcnt lgkmcnt(0)"                                                  \
      : "=v"(T0), "=v"(T1), "=v"(T2), "=v"(T3),                               \
        "=v"(T4), "=v"(T5), "=v"(T6), "=v"(T7)                                \
      : "v"(ra_) : "memory"); }

#define BUILDA(A_, TA, TB, WA, WB_)                                           \
  { uivec4 au_;                                                               \
    au_.x = cvtpk(__uint_as_float(TA.x << 16) * WA.x,                         \
                  __uint_as_float(TA.x & 0xFFFF0000u) * WA.y);                \
    au_.y = cvtpk(__uint_as_float(TA.y << 16) * WA.z,                         \
                  __uint_as_float(TA.y & 0xFFFF0000u) * WA.w);                \
    au_.z = cvtpk(__uint_as_float(TB.x << 16) * WB_.x,                        \
                  __uint_as_float(TB.x & 0xFFFF0000u) * WB_.y);               \
    au_.w = cvtpk(__uint_as_float(TB.y << 16) * WB_.z,                        \
                  __uint_as_float(TB.y & 0xFFFF0000u) * WB_.w);               \
    A_ = __builtin_bit_cast(s16x8, au_); }

#define MFMAW(WBUF)                                                           \
  { f32x4 dd[8];                                                              \
    _Pragma("unroll")                                                         \
    for (int tl = 0; tl < 8; ++tl) {                                          \
      f32x4 z = {0.f, 0.f, 0.f, 0.f};                                         \
      z = __builtin_amdgcn_mfma_f32_16x16x32_bf16(A0, Bf[tl][0], z, 0, 0, 0); \
      z = __builtin_amdgcn_mfma_f32_16x16x32_bf16(A1, Bf[tl][1], z, 0, 0, 0); \
      z = __builtin_amdgcn_mfma_f32_16x16x32_bf16(A2, Bf[tl][2], z, 0, 0, 0); \
      z = __builtin_amdgcn_mfma_f32_16x16x32_bf16(A3, Bf[tl][3], z, 0, 0, 0); \
      dd[tl] = z;                                                             \
    }                                                                         \
    _Pragma("unroll")                                                         \
    for (int tl = 0; tl < 8; ++tl) {                                          \
      uivec2 w_;                                                              \
      w_.x = cvtpk(dd[tl][0], dd[tl][1]);                                     \
      w_.y = cvtpk(dd[tl][2], dd[tl][3]);                                     \
      *(uivec2*)(smem + wroff + (WBUF) * 4096 + tl * 512) = w_;               \
    } }

#define MULT(RBUF, WBUF, S, REN, PT, PSLOT)                                   \
  { asm volatile("s_waitcnt lgkmcnt(0)" ::: "memory");                        \
    uivec2 t0, t1, t2, t3, t4, t5, t6, t7;                                    \
    TRREAD8(RBUF, t0, t1, t2, t3, t4, t5, t6, t7)                             \
    float4 we0 = expf4(S##0), we1 = expf4(S##1), we2 = expf4(S##2),           \
           we3 = expf4(S##3), we4 = expf4(S##4), we5 = expf4(S##5),           \
           we6 = expf4(S##6), we7 = expf4(S##7);                              \
    if (REN) {                                                                \
      float pf = __uint_as_float(__builtin_amdgcn_readfirstlane(t0.x << 16)); \
      Kacc += __logf(pf);                                                     \
      float rs = __builtin_amdgcn_rcpf(pf);                                   \
      we0 = mul4(we0, rs); we1 = mul4(we1, rs); we2 = mul4(we2, rs);          \
      we3 = mul4(we3, rs); we4 = mul4(we4, rs); we5 = mul4(we5, rs);          \
      we6 = mul4(we6, rs); we7 = mul4(we7, rs);                               \
    }                                                                         \
    s16x8 A0, A1, A2, A3;                                                     \
    BUILDA(A0, t0, t1, we0, we1)                                              \
    BUILDA(A1, t2, t3, we2, we3)                                              \
    BUILDA(A2, t4, t5, we4, we5)                                              \
    BUILDA(A3, t6, t7, we6, we7)                                              \
    MFMAW(WBUF)                                                               \
    if ((PT) >= 0) LOADSLOT(PSLOT, PT) }

  float4 SA0, SA1, SA2, SA3, SA4, SA5, SA6, SA7;
  float4 SB0, SB1, SB2, SB3, SB4, SB5, SB6, SB7;
  const int tau1 = FWD ? (t_lo - 1) : t_hi;
  const int tau2 = FWD ? t_lo : (t_hi - 1);
  LOADSLOT(SB, tau1)
  LOADSLOT(SA, tau2)

  // ---- MULT_1: raw_0 = ones; A = wex(tau1) (or splat 1.0 for fwd probes) ----
  {
    s16x8 A0, A1, A2, A3;
    if (FWD && c > 0) {
      uivec4 au; au.x = au.y = au.z = au.w = 0x3F803F80u;
      A0 = __builtin_bit_cast(s16x8, au); A1 = A0; A2 = A0; A3 = A0;
    } else {
      float4 we0 = expf4(SB0), we1 = expf4(SB1), we2 = expf4(SB2),
             we3 = expf4(SB3), we4 = expf4(SB4), we5 = expf4(SB5),
             we6 = expf4(SB6), we7 = expf4(SB7);
      uivec4 a0; a0.x = cvtpk(we0.x, we0.y); a0.y = cvtpk(we0.z, we0.w);
      a0.z = cvtpk(we1.x, we1.y); a0.w = cvtpk(we1.z, we1.w);
      uivec4 a1; a1.x = cvtpk(we2.x, we2.y); a1.y = cvtpk(we2.z, we2.w);
      a1.z = cvtpk(we3.x, we3.y); a1.w = cvtpk(we3.z, we3.w);
      uivec4 a2; a2.x = cvtpk(we4.x, we4.y); a2.y = cvtpk(we4.z, we4.w);
      a2.z = cvtpk(we5.x, we5.y); a2.w = cvtpk(we5.z, we5.w);
      uivec4 a3; a3.x = cvtpk(we6.x, we6.y); a3.y = cvtpk(we6.z, we6.w);
      a3.z = cvtpk(we7.x, we7.y); a3.w = cvtpk(we7.z, we7.w);
      A0 = __builtin_bit_cast(s16x8, a0); A1 = __builtin_bit_cast(s16x8, a1);
      A2 = __builtin_bit_cast(s16x8, a2); A3 = __builtin_bit_cast(s16x8, a3);
    }
    MFMAW(1)
    const int tau3 = FWD ? (t_lo + 1) : (t_hi - 2);
    LOADSLOT(SB, tau3)
  }

  // ---- MULTs 2..n (pairs), renorm at k=9 and k=15 ----
  for (int k = 2; k + 1 <= n; k += 2) {
    const int ta = FWD ? (t_lo + k) : (t_hi - k - 1);            // tau(k+2)
    MULT(1, 0, SA, false, ta, SA)
    const bool ren = ((k + 1) == 9) || ((k + 1) == 15);
    const int tb = (k + 3 <= n + 1) ? (FWD ? (t_lo + k + 1) : (t_hi - k - 2))
                                    : -1;                        // tau(k+3)
    MULT(0, 1, SB, ren, tb, SB)
  }
  if ((n & 1) == 0) {            // n = 16: final even MULT
    MULT(1, 0, SA, false, -1, SA)
  }

  // ---- final: tr-read raw_n, scale (fwd: wex(t_hi); bwd: 1), store ----
  {
    asm volatile("s_waitcnt lgkmcnt(0)" ::: "memory");
    uivec2 t0, t1, t2, t3, t4, t5, t6, t7;
    TRREAD8((n & 1), t0, t1, t2, t3, t4, t5, t6, t7)
    float4 wf0, wf1, wf2, wf3, wf4, wf5, wf6, wf7;
    if (FWD) {   // slot parity (n+1)&1 = SB (n=16 always for fwd), tau = t_hi
      wf0 = expf4(SB0); wf1 = expf4(SB1); wf2 = expf4(SB2); wf3 = expf4(SB3);
      wf4 = expf4(SB4); wf5 = expf4(SB5); wf6 = expf4(SB6); wf7 = expf4(SB7);
    } else {
      float4 one = {1.f, 1.f, 1.f, 1.f};
      wf0 = wf1 = wf2 = wf3 = wf4 = wf5 = wf6 = wf7 = one;
    }
    const int cs = FWD ? c : (c - 1);
    float* rp0 = wsf + (FWD ? WS_RV : WS_BV)
               + ((size_t)(b0 + l15) * NR + cs) * 128 + 4 * q;
#define STOREV(I, T_, W_)                                                     \
    { float4 o_;                                                              \
      o_.x = __uint_as_float(T_.x << 16) * W_.x;                              \
      o_.y = __uint_as_float(T_.x & 0xFFFF0000u) * W_.y;                      \
      o_.z = __uint_as_float(T_.y << 16) * W_.z;                              \
      o_.w = __uint_as_float(T_.y & 0xFFFF0000u) * W_.w;                      \
      *(float4*)(rp0 + 16 * (I)) = o_; }
    STOREV(0, t0, wf0) STOREV(1, t1, wf1) STOREV(2, t2, wf2) STOREV(3, t3, wf3)
    STOREV(4, t4, wf4) STOREV(5, t5, wf5) STOREV(6, t6, wf6) STOREV(7, t7, wf7)
#undef STOREV
    if (q == 0) {
      float* kp = wsf + (FWD ? WS_KR : WS_KB);
      kp[(b0 + l15) * NR + cs] = Kacc;
    }
  }
#undef MULT
#undef MFMAW
#undef BUILDA
#undef TRREAD8
#undef LOADSLOT
}

// logZ = log(r0.b1)+Kr0+Kb1 + sum_{c=1..NR-1}[log(rc.b_{c+1}) + Kb_{c+1} - log(sum rc)]
__global__ __launch_bounds__(64) void crf_stitch(
    const float* __restrict__ wsf, float* __restrict__ out)
{
  const int b = blockIdx.x, j = threadIdx.x;
  const float* RV = wsf + WS_RV + (size_t)b * NR * 128;
  const float* BV = wsf + WS_BV + (size_t)b * NR * 128;
  const float* Kr = wsf + WS_KR + b * NR;
  const float* Kb = wsf + WS_KB + b * NR;
  float lz;
  {
    float d = RV[j] * BV[j] + RV[j + 64] * BV[j + 64];
    #pragma unroll
    for (int o = 32; o; o >>= 1) d += __shfl_xor(d, o);
    lz = __logf(d) + Kr[0] + Kb[0];
  }
  #pragma unroll
  for (int cc = 1; cc < NR; ++cc) {
    float d = RV[cc*128 + j] * BV[cc*128 + j] + RV[cc*128 + j + 64] * BV[cc*128 + j + 64];
    float s = RV[cc*128 + j] + RV[cc*128 + j + 64];
    #pragma unroll
    for (int o = 32; o; o >>= 1) { d += __shfl_xor(d, o); s += __shfl_xor(s, o); }
    lz += __logf(d) - __logf(s) + Kb[cc];
  }
  if (j == 0) out[b] = lz - wsf[WS_PT + b] - wsf[WS_TR + b];
}

extern "C" void kernel_launch(void* const* d_in, const int* in_sizes, int n_in,
                              void* d_out, int out_size, void* d_ws, size_t ws_size,
                              hipStream_t stream) {
  const float* y_true = (const float*)d_in[0];
  const float* y_pred = (const float*)d_in[1];
  const float* trans  = (const float*)d_in[2];
  float* out = (float*)d_out;
  float* wsf = (float*)d_ws;
  crf_main<<<dim3(2 * NRECB + (NSCORE - NRECB)), dim3(256), 0, stream>>>(
      y_true, y_pred, trans, wsf);
  crf_stitch<<<dim3(256), dim3(64), 0, stream>>>(wsf, out);
}

// Round 13
// 66.965 us; speedup vs baseline: 1.0590x; 1.0590x over previous
//
#include <hip/hip_runtime.h>

typedef float    f32x4  __attribute__((ext_vector_type(4)));
typedef short    s16x8  __attribute__((ext_vector_type(8)));
typedef unsigned uivec2 __attribute__((ext_vector_type(2)));
typedef unsigned uivec4 __attribute__((ext_vector_type(4)));

#define Tt 512
#define Ll 128
#define CH 32
#define CL 16
#define NR 31
#define NRECB 248        // recursion blocks (4 independent waves each = 992 runs)

// workspace float offsets
#define WS_PTP 0                         // [256][8] point-score partials
#define WS_KR  2048                      // [256][NR] fwd log-scale
#define WS_KB  (2048 + 256*NR)           // [256][NR] bwd log-scale
#define WS_RV  (2048 + 2*256*NR)         // [256][NR][128] fwd result vectors
#define WS_BV  (WS_RV + 256*NR*128)      // [256][NR][128] bwd result vectors
#define WS_END (WS_BV + 256*NR*128)      // = 2049536 floats
#define WS_LAB_BYTES ((size_t)WS_END * 4)   // uchar labels [256][512]

__device__ __forceinline__ ushort bf16rn(float f) {   // RNE f32->bf16 (positive)
  unsigned u = __float_as_uint(f);
  u += 0x7FFFu + ((u >> 16) & 1u);
  return (ushort)(u >> 16);
}
__device__ __forceinline__ unsigned cvtpk(float a, float b) {
  unsigned d;
  asm("v_cvt_pk_bf16_f32 %0, %1, %2" : "=v"(d) : "v"(a), "v"(b));
  return d;
}
__device__ __forceinline__ float4 expf4(float4 v) {
  float4 r; r.x = __expf(v.x); r.y = __expf(v.y); r.z = __expf(v.z); r.w = __expf(v.w);
  return r;
}
__device__ __forceinline__ float4 mul4(float4 v, float s) {
  v.x *= s; v.y *= s; v.z *= s; v.w *= s; return v;
}

// ================= recursion kernel (round-12 math, absmax 0.0) =================
// 248 blocks x 4 INDEPENDENT waves = 992 chunk runs. Per step U(16x128)@E =
// 32 MFMAs in one wave; E in 128 VGPRs; U via wave-private LDS with
// ds_read_b64_tr_b16 HW transpose; emission scaling A-side; pivot renorm at
// k=9,15 via readfirstlane. Zero barriers. Runs FIRST -> warms L3 with y_pred.
__global__ __attribute__((amdgpu_flat_work_group_size(256, 256),
                          amdgpu_waves_per_eu(1)))
void crf_rec(const float* __restrict__ yp_g, const float* __restrict__ tr_g,
             float* __restrict__ wsf)
{
  __shared__ __align__(16) char smem[32768];
  const int tid = threadIdx.x, wv = tid >> 6, l = tid & 63;

  const int task = blockIdx.x * 4 + wv;   // 0..991
  const bool FWD = task < 496;
  int g, c;
  if (FWD) { g = task / 31; c = task % 31; }
  else     { int t2 = task - 496; g = t2 / 31; c = t2 % 31 + 1; }
  const int b0  = g * 16;
  const int l15 = l & 15, q = l >> 4;
  const int t_hi = (c == CH - 1) ? (Tt - 1) : (c * CL + CL);
  const int t_lo = c * CL + 1;
  const int n    = FWD ? CL : (t_hi - t_lo + 1);   // 16, or 15 for bwd c=31

  s16x8 Bf[8][4];
  if (FWD) {
    #pragma unroll
    for (int kt = 0; kt < 4; ++kt)
      #pragma unroll
      for (int e = 0; e < 8; ++e) {
        const int jin = 32 * kt + 16 * (e >> 2) + 4 * q + (e & 3);
        const float* rp_ = tr_g + jin * Ll + l15;
        #pragma unroll
        for (int tl = 0; tl < 8; ++tl)
          Bf[tl][kt][e] = (short)bf16rn(__expf(rp_[16 * tl]));
      }
  } else {
    #pragma unroll
    for (int tl = 0; tl < 8; ++tl) {
      const float* rp_ = tr_g + (l15 + 16 * tl) * Ll + 4 * q;
      #pragma unroll
      for (int kt = 0; kt < 4; ++kt)
        #pragma unroll
        for (int r = 0; r < 2; ++r) {
          float4 tv = *(const float4*)(rp_ + 32 * kt + 16 * r);
          Bf[tl][kt][4 * r + 0] = (short)bf16rn(__expf(tv.x));
          Bf[tl][kt][4 * r + 1] = (short)bf16rn(__expf(tv.y));
          Bf[tl][kt][4 * r + 2] = (short)bf16rn(__expf(tv.z));
          Bf[tl][kt][4 * r + 3] = (short)bf16rn(__expf(tv.w));
        }
    }
  }

  const unsigned sbase = (unsigned)(size_t)(&smem[0]);
  const unsigned wvoff = (unsigned)(wv * 8192);
  const unsigned lane8 = (unsigned)(l * 8);
  const int wroff = wv * 8192 + l15 * 32 + q * 8;
  const float* emb = yp_g + (size_t)(b0 + l15) * (Tt * Ll) + 4 * q;
  float Kacc = 0.f;

#define LOADSLOT(S, TAU)                                                      \
  { const float* ep_ = emb + (size_t)(TAU) * Ll;                              \
    S##0 = *(const float4*)(ep_ + 0);   S##1 = *(const float4*)(ep_ + 16);    \
    S##2 = *(const float4*)(ep_ + 32);  S##3 = *(const float4*)(ep_ + 48);    \
    S##4 = *(const float4*)(ep_ + 64);  S##5 = *(const float4*)(ep_ + 80);    \
    S##6 = *(const float4*)(ep_ + 96);  S##7 = *(const float4*)(ep_ + 112); }

#define TRREAD8(RBUF, T0,T1,T2,T3,T4,T5,T6,T7)                                \
  { unsigned ra_ = sbase + wvoff + (unsigned)((RBUF) * 4096) + lane8;         \
    asm volatile(                                                             \
      "ds_read_b64_tr_b16 %0, %8 offset:0\n\t"                                \
      "ds_read_b64_tr_b16 %1, %8 offset:512\n\t"                              \
      "ds_read_b64_tr_b16 %2, %8 offset:1024\n\t"                             \
      "ds_read_b64_tr_b16 %3, %8 offset:1536\n\t"                             \
      "ds_read_b64_tr_b16 %4, %8 offset:2048\n\t"                             \
      "ds_read_b64_tr_b16 %5, %8 offset:2560\n\t"                             \
      "ds_read_b64_tr_b16 %6, %8 offset:3072\n\t"                             \
      "ds_read_b64_tr_b16 %7, %8 offset:3584\n\t"                             \
      "s_waitcnt lgkmcnt(0)"                                                  \
      : "=v"(T0), "=v"(T1), "=v"(T2), "=v"(T3),                               \
        "=v"(T4), "=v"(T5), "=v"(T6), "=v"(T7)                                \
      : "v"(ra_) : "memory"); }

#define BUILDA(A_, TA, TB, WA, WB_)                                           \
  { uivec4 au_;                                                               \
    au_.x = cvtpk(__uint_as_float(TA.x << 16) * WA.x,                         \
                  __uint_as_float(TA.x & 0xFFFF0000u) * WA.y);                \
    au_.y = cvtpk(__uint_as_float(TA.y << 16) * WA.z,                         \
                  __uint_as_float(TA.y & 0xFFFF0000u) * WA.w);                \
    au_.z = cvtpk(__uint_as_float(TB.x << 16) * WB_.x,                        \
                  __uint_as_float(TB.x & 0xFFFF0000u) * WB_.y);               \
    au_.w = cvtpk(__uint_as_float(TB.y << 16) * WB_.z,                        \
                  __uint_as_float(TB.y & 0xFFFF0000u) * WB_.w);               \
    A_ = __builtin_bit_cast(s16x8, au_); }

#define MFMAW(WBUF)                                                           \
  { f32x4 dd[8];                                                              \
    _Pragma("unroll")                                                         \
    for (int tl = 0; tl < 8; ++tl) {                                          \
      f32x4 z = {0.f, 0.f, 0.f, 0.f};                                         \
      z = __builtin_amdgcn_mfma_f32_16x16x32_bf16(A0, Bf[tl][0], z, 0, 0, 0); \
      z = __builtin_amdgcn_mfma_f32_16x16x32_bf16(A1, Bf[tl][1], z, 0, 0, 0); \
      z = __builtin_amdgcn_mfma_f32_16x16x32_bf16(A2, Bf[tl][2], z, 0, 0, 0); \
      z = __builtin_amdgcn_mfma_f32_16x16x32_bf16(A3, Bf[tl][3], z, 0, 0, 0); \
      dd[tl] = z;                                                             \
    }                                                                         \
    _Pragma("unroll")                                                         \
    for (int tl = 0; tl < 8; ++tl) {                                          \
      uivec2 w_;                                                              \
      w_.x = cvtpk(dd[tl][0], dd[tl][1]);                                     \
      w_.y = cvtpk(dd[tl][2], dd[tl][3]);                                     \
      *(uivec2*)(smem + wroff + (WBUF) * 4096 + tl * 512) = w_;               \
    } }

#define MULT(RBUF, WBUF, S, REN, PT, PSLOT)                                   \
  { asm volatile("s_waitcnt lgkmcnt(0)" ::: "memory");                        \
    uivec2 t0, t1, t2, t3, t4, t5, t6, t7;                                    \
    TRREAD8(RBUF, t0, t1, t2, t3, t4, t5, t6, t7)                             \
    float4 we0 = expf4(S##0), we1 = expf4(S##1), we2 = expf4(S##2),           \
           we3 = expf4(S##3), we4 = expf4(S##4), we5 = expf4(S##5),           \
           we6 = expf4(S##6), we7 = expf4(S##7);                              \
    if (REN) {                                                                \
      float pf = __uint_as_float(__builtin_amdgcn_readfirstlane(t0.x << 16)); \
      Kacc += __logf(pf);                                                     \
      float rs = __builtin_amdgcn_rcpf(pf);                                   \
      we0 = mul4(we0, rs); we1 = mul4(we1, rs); we2 = mul4(we2, rs);          \
      we3 = mul4(we3, rs); we4 = mul4(we4, rs); we5 = mul4(we5, rs);          \
      we6 = mul4(we6, rs); we7 = mul4(we7, rs);                               \
    }                                                                         \
    s16x8 A0, A1, A2, A3;                                                     \
    BUILDA(A0, t0, t1, we0, we1)                                              \
    BUILDA(A1, t2, t3, we2, we3)                                              \
    BUILDA(A2, t4, t5, we4, we5)                                              \
    BUILDA(A3, t6, t7, we6, we7)                                              \
    MFMAW(WBUF)                                                               \
    if ((PT) >= 0) LOADSLOT(PSLOT, PT) }

  float4 SA0, SA1, SA2, SA3, SA4, SA5, SA6, SA7;
  float4 SB0, SB1, SB2, SB3, SB4, SB5, SB6, SB7;
  const int tau1 = FWD ? (t_lo - 1) : t_hi;
  const int tau2 = FWD ? t_lo : (t_hi - 1);
  LOADSLOT(SB, tau1)
  LOADSLOT(SA, tau2)

  {
    s16x8 A0, A1, A2, A3;
    if (FWD && c > 0) {
      uivec4 au; au.x = au.y = au.z = au.w = 0x3F803F80u;
      A0 = __builtin_bit_cast(s16x8, au); A1 = A0; A2 = A0; A3 = A0;
    } else {
      float4 we0 = expf4(SB0), we1 = expf4(SB1), we2 = expf4(SB2),
             we3 = expf4(SB3), we4 = expf4(SB4), we5 = expf4(SB5),
             we6 = expf4(SB6), we7 = expf4(SB7);
      uivec4 a0; a0.x = cvtpk(we0.x, we0.y); a0.y = cvtpk(we0.z, we0.w);
      a0.z = cvtpk(we1.x, we1.y); a0.w = cvtpk(we1.z, we1.w);
      uivec4 a1; a1.x = cvtpk(we2.x, we2.y); a1.y = cvtpk(we2.z, we2.w);
      a1.z = cvtpk(we3.x, we3.y); a1.w = cvtpk(we3.z, we3.w);
      uivec4 a2; a2.x = cvtpk(we4.x, we4.y); a2.y = cvtpk(we4.z, we4.w);
      a2.z = cvtpk(we5.x, we5.y); a2.w = cvtpk(we5.z, we5.w);
      uivec4 a3; a3.x = cvtpk(we6.x, we6.y); a3.y = cvtpk(we6.z, we6.w);
      a3.z = cvtpk(we7.x, we7.y); a3.w = cvtpk(we7.z, we7.w);
      A0 = __builtin_bit_cast(s16x8, a0); A1 = __builtin_bit_cast(s16x8, a1);
      A2 = __builtin_bit_cast(s16x8, a2); A3 = __builtin_bit_cast(s16x8, a3);
    }
    MFMAW(1)
    const int tau3 = FWD ? (t_lo + 1) : (t_hi - 2);
    LOADSLOT(SB, tau3)
  }

  for (int k = 2; k + 1 <= n; k += 2) {
    const int ta = FWD ? (t_lo + k) : (t_hi - k - 1);
    MULT(1, 0, SA, false, ta, SA)
    const bool ren = ((k + 1) == 9) || ((k + 1) == 15);
    const int tb = (k + 3 <= n + 1) ? (FWD ? (t_lo + k + 1) : (t_hi - k - 2))
                                    : -1;
    MULT(0, 1, SB, ren, tb, SB)
  }
  if ((n & 1) == 0) {
    MULT(1, 0, SA, false, -1, SA)
  }

  {
    asm volatile("s_waitcnt lgkmcnt(0)" ::: "memory");
    uivec2 t0, t1, t2, t3, t4, t5, t6, t7;
    TRREAD8((n & 1), t0, t1, t2, t3, t4, t5, t6, t7)
    float4 wf0, wf1, wf2, wf3, wf4, wf5, wf6, wf7;
    if (FWD) {
      wf0 = expf4(SB0); wf1 = expf4(SB1); wf2 = expf4(SB2); wf3 = expf4(SB3);
      wf4 = expf4(SB4); wf5 = expf4(SB5); wf6 = expf4(SB6); wf7 = expf4(SB7);
    } else {
      float4 one = {1.f, 1.f, 1.f, 1.f};
      wf0 = wf1 = wf2 = wf3 = wf4 = wf5 = wf6 = wf7 = one;
    }
    const int cs = FWD ? c : (c - 1);
    float* rp0 = wsf + (FWD ? WS_RV : WS_BV)
               + ((size_t)(b0 + l15) * NR + cs) * 128 + 4 * q;
#define STOREV(I, T_, W_)                                                     \
    { float4 o_;                                                              \
      o_.x = __uint_as_float(T_.x << 16) * W_.x;                              \
      o_.y = __uint_as_float(T_.x & 0xFFFF0000u) * W_.y;                      \
      o_.z = __uint_as_float(T_.y << 16) * W_.z;                              \
      o_.w = __uint_as_float(T_.y & 0xFFFF0000u) * W_.w;                      \
      *(float4*)(rp0 + 16 * (I)) = o_; }
    STOREV(0, t0, wf0) STOREV(1, t1, wf1) STOREV(2, t2, wf2) STOREV(3, t3, wf3)
    STOREV(4, t4, wf4) STOREV(5, t5, wf5) STOREV(6, t6, wf6) STOREV(7, t7, wf7)
#undef STOREV
    if (q == 0) {
      float* kp = wsf + (FWD ? WS_KR : WS_KB);
      kp[(b0 + l15) * NR + cs] = Kacc;
    }
  }
#undef MULT
#undef MFMAW
#undef BUILDA
#undef TRREAD8
#undef LOADSLOT
}

// ================= score kernel: full-occupancy streaming =================
// 2048 blocks: b = bid>>3, T-segment seg = bid&7 (64 steps). ~24 VGPR, 16B
// LDS -> 8 blocks/CU co-resident = 32 waves/CU; y_pred from L3 (warmed by
// crf_rec), y_true from HBM. Writes uchar labels + per-(b,seg) point partial.
__global__ __launch_bounds__(256) void crf_score(
    const float* __restrict__ yt_g, const float* __restrict__ yp_g,
    float* __restrict__ wsf, unsigned char* __restrict__ lab_g)
{
  __shared__ float red[4];
  const int bid = blockIdx.x;
  const int b = bid >> 3, seg = bid & 7;
  const int tid = threadIdx.x, wv = tid >> 6, l = tid & 63;
  const float4* yp4 = (const float4*)(yp_g + ((size_t)b * Tt + seg * 64) * Ll);
  const float4* yt4 = (const float4*)(yt_g + ((size_t)b * Tt + seg * 64) * Ll);
  unsigned char* lb = lab_g + b * Tt + seg * 64;
  float pt = 0.f;
  #pragma unroll
  for (int i = 0; i < 8; ++i) {
    int f = tid + i * 256;              // 0..2047 float4s in this segment
    float4 a = yp4[f], y = yt4[f];
    pt += a.x * y.x + a.y * y.y + a.z * y.z + a.w * y.w;
    int t = f >> 5, jb = (f & 31) << 2;
    if (y.x > .5f) lb[t] = (unsigned char)jb;
    if (y.y > .5f) lb[t] = (unsigned char)(jb + 1);
    if (y.z > .5f) lb[t] = (unsigned char)(jb + 2);
    if (y.w > .5f) lb[t] = (unsigned char)(jb + 3);
  }
  #pragma unroll
  for (int o = 32; o; o >>= 1) pt += __shfl_xor(pt, o);
  if (l == 0) red[wv] = pt;
  __syncthreads();
  if (tid == 0) wsf[WS_PTP + b * 8 + seg] = red[0] + red[1] + red[2] + red[3];
}

// ================= stitch: seams + trans gather + point sum =================
__global__ __launch_bounds__(64) void crf_stitch(
    const float* __restrict__ wsf, const unsigned char* __restrict__ lab_g,
    const float* __restrict__ tr_g, float* __restrict__ out)
{
  const int b = blockIdx.x, j = threadIdx.x;
  const float* RV = wsf + WS_RV + (size_t)b * NR * 128;
  const float* BV = wsf + WS_BV + (size_t)b * NR * 128;
  const float* Kr = wsf + WS_KR + b * NR;
  const float* Kb = wsf + WS_KB + b * NR;
  float lz;
  {
    float d = RV[j] * BV[j] + RV[j + 64] * BV[j + 64];
    #pragma unroll
    for (int o = 32; o; o >>= 1) d += __shfl_xor(d, o);
    lz = __logf(d) + Kr[0] + Kb[0];
  }
  #pragma unroll
  for (int cc = 1; cc < NR; ++cc) {
    float d = RV[cc*128 + j] * BV[cc*128 + j] + RV[cc*128 + j + 64] * BV[cc*128 + j + 64];
    float s = RV[cc*128 + j] + RV[cc*128 + j + 64];
    #pragma unroll
    for (int o = 32; o; o >>= 1) { d += __shfl_xor(d, o); s += __shfl_xor(s, o); }
    lz += __logf(d) - __logf(s) + Kb[cc];
  }
  // trans score from labels + point partials
  const unsigned char* lb = lab_g + b * Tt;
  float tp = (j < 8) ? wsf[WS_PTP + b * 8 + j] : 0.f;
  #pragma unroll
  for (int i = 0; i < 8; ++i) {
    int t = j + i * 64;
    if (t < Tt - 1) tp += tr_g[(int)lb[t] * Ll + (int)lb[t + 1]];
  }
  #pragma unroll
  for (int o = 32; o; o >>= 1) tp += __shfl_xor(tp, o);
  if (j == 0) out[b] = lz - tp;
}

extern "C" void kernel_launch(void* const* d_in, const int* in_sizes, int n_in,
                              void* d_out, int out_size, void* d_ws, size_t ws_size,
                              hipStream_t stream) {
  const float* y_true = (const float*)d_in[0];
  const float* y_pred = (const float*)d_in[1];
  const float* trans  = (const float*)d_in[2];
  float* out = (float*)d_out;
  float* wsf = (float*)d_ws;
  unsigned char* lab = (unsigned char*)d_ws + WS_LAB_BYTES;
  crf_rec  <<<dim3(NRECB), dim3(256), 0, stream>>>(y_pred, trans, wsf);
  crf_score<<<dim3(2048),  dim3(256), 0, stream>>>(y_true, y_pred, wsf, lab);
  crf_stitch<<<dim3(256),  dim3(64),  0, stream>>>(wsf, lab, trans, out);
}